// Round 6
// baseline (67.100 us; speedup 1.0000x reference)
//
#include <hip/hip_runtime.h>

// Problem constants (from reference): B=4096, N_IN=64, N_OUT=64, M=4096.
#define BATCH 4096
#define NIN   64
#define NOUT  64
#define M_TOT (NIN * NOUT)

// ---------------------------------------------------------------------------
// Kernel 1: build WM from (aW, uW, tW). One thread per m = j*64 + k.
// Transposed layout for coalesced main-kernel loads:
//   WT[(j*3 + q)*64 + k] = row q of matrix (j,k)  (quad = (Rq0,Rq1,Rq2,tq))
// bottom row [0,0,0,1] implicit. 192 KiB in d_ws.
// ---------------------------------------------------------------------------
__global__ __launch_bounds__(256) void build_wm_kernel(
    const float* __restrict__ aW, const float* __restrict__ uW,
    const float* __restrict__ tW, float4* __restrict__ WT) {
  int m = blockIdx.x * 256 + threadIdx.x;
  if (m >= M_TOT) return;
  int j = m >> 6, k = m & 63;

  float a  = aW[m];
  float ux = 1.f / (1.f + expf(-uW[3 * m + 0]));
  float uy = 1.f / (1.f + expf(-uW[3 * m + 1]));
  float uz = 1.f / (1.f + expf(-uW[3 * m + 2]));
  float inv = 1.f / sqrtf(ux * ux + uy * uy + uz * uz);
  ux *= inv; uy *= inv; uz *= inv;

  float sa = sinf(a), ca = cosf(a);
  float xx = ux * ux, yy = uy * uy, zz = uz * uz;
  float xy = ux * uy, xz = ux * uz, yz = uy * uz;

  float R00 = ca * (1.f - xx) + xx;
  float R01 = -sa * uz + ca * (-xy) + xy;
  float R02 =  sa * uy + ca * (-xz) + xz;
  float R10 =  sa * uz + ca * (-xy) + xy;
  float R11 = ca * (1.f - yy) + yy;
  float R12 = -sa * ux + ca * (-yz) + yz;
  float R20 = -sa * uy + ca * (-xz) + xz;
  float R21 =  sa * ux + ca * (-yz) + yz;
  float R22 = ca * (1.f - zz) + zz;

  float t0 = tW[3 * m + 0], t1 = tW[3 * m + 1], t2 = tW[3 * m + 2];

  WT[(j * 3 + 0) * 64 + k] = make_float4(R00, R01, R02, t0);
  WT[(j * 3 + 1) * 64 + k] = make_float4(R10, R11, R12, t1);
  WT[(j * 3 + 2) * 64 + k] = make_float4(R20, R21, R22, t2);
}

// ---------------------------------------------------------------------------
// Kernel 2: chain product, 2-way split over j via associativity.
// Block = 128 threads = 2 waves, one batch row b = blockIdx.x:
//   wave 0: j in [0,32)  -> P0       wave 1: j in [32,64) -> P1
// lane = k. NEW (round 6): the block's I slice (256 float4 = 4 KiB) is
// staged into LDS once with 2 coalesced 2-KiB loads — HBM latency paid once
// per block instead of 32x per wave in-loop (round 5: in-loop s_loads with
// ~2-iter lookahead vs ~900cy HBM latency = the measured 40% stall time).
// In-loop I reads are wave-uniform ds_read_b128 broadcasts (conflict-free).
// W loads lane-coalesced (1 KiB/instr), L1/L2-resident (shared by all
// blocks). O = P0 @ P1 via padded LDS. LDS total 8.8 KiB -> 16 blocks/CU.
// NO register cap (round-2's (256,8) forced VGPR=32 -> 200MB scratch spill).
// ---------------------------------------------------------------------------

// write A-row (4 dests) from I-row r and affine W rows W0..W2
#define IMUL_TO(D0, D1, D2, D3, r, W0, W1, W2)                       \
  D0 = r.x * W0.x + r.y * W1.x + r.z * W2.x;                         \
  D1 = r.x * W0.y + r.y * W1.y + r.z * W2.y;                         \
  D2 = r.x * W0.z + r.y * W1.z + r.z * W2.z;                         \
  D3 = r.x * W0.w + r.y * W1.w + r.z * W2.w + r.w;

#define CMUL_ROW(x)                                                            \
  {                                                                            \
    float t0 = c[x*4+0]*A00 + c[x*4+1]*A10 + c[x*4+2]*A20 + c[x*4+3]*A30;      \
    float t1 = c[x*4+0]*A01 + c[x*4+1]*A11 + c[x*4+2]*A21 + c[x*4+3]*A31;      \
    float t2 = c[x*4+0]*A02 + c[x*4+1]*A12 + c[x*4+2]*A22 + c[x*4+3]*A32;      \
    float t3 = c[x*4+0]*A03 + c[x*4+1]*A13 + c[x*4+2]*A23 + c[x*4+3]*A33;      \
    c[x*4+0] = t0; c[x*4+1] = t1; c[x*4+2] = t2; c[x*4+3] = t3;                \
  }

__global__ __launch_bounds__(128) void chain_kernel(
    const float4* __restrict__ I4, const float4* __restrict__ WT,
    float4* __restrict__ O4) {
  const int t    = threadIdx.x;
  const int lane = t & 63;
  const int half = t >> 6;  // 0: j in [0,32), 1: j in [32,64)
  const int b    = (int)blockIdx.x;

  __shared__ float4 ILDS[256];    // whole I[b] slice: 64 j x 4 rows
  __shared__ float  P[64][17];    // combine buffer, padded stride 17

  // stage I[b] into LDS: 2 coalesced 2-KiB loads
  const float4* __restrict__ Isrc = I4 + (size_t)b * (NIN * 4);
  ILDS[t]       = Isrc[t];
  ILDS[t + 128] = Isrc[t + 128];
  __syncthreads();

  const float4* __restrict__ Wb = WT + (size_t)(half * 32 * 3) * 64 + lane;
  const int ibase = half * 128;   // this wave's 32 j x 4 rows in ILDS

  float c[16];
  {  // peeled j=0: c = A directly (skip identity multiply)
    float4 w0 = Wb[0], w1 = Wb[64], w2 = Wb[128];
    float4 r0 = ILDS[ibase + 0], r1 = ILDS[ibase + 1];
    float4 r2 = ILDS[ibase + 2], r3 = ILDS[ibase + 3];
    IMUL_TO(c[0],  c[1],  c[2],  c[3],  r0, w0, w1, w2)
    IMUL_TO(c[4],  c[5],  c[6],  c[7],  r1, w0, w1, w2)
    IMUL_TO(c[8],  c[9],  c[10], c[11], r2, w0, w1, w2)
    IMUL_TO(c[12], c[13], c[14], c[15], r3, w0, w1, w2)
  }

#pragma unroll 4
  for (int j = 1; j < 32; ++j) {
    float4 w0 = Wb[j * 192], w1 = Wb[j * 192 + 64], w2 = Wb[j * 192 + 128];
    float4 r0 = ILDS[ibase + j * 4 + 0], r1 = ILDS[ibase + j * 4 + 1];
    float4 r2 = ILDS[ibase + j * 4 + 2], r3 = ILDS[ibase + j * 4 + 3];
    float A00, A01, A02, A03, A10, A11, A12, A13;
    float A20, A21, A22, A23, A30, A31, A32, A33;
    IMUL_TO(A00, A01, A02, A03, r0, w0, w1, w2)
    IMUL_TO(A10, A11, A12, A13, r1, w0, w1, w2)
    IMUL_TO(A20, A21, A22, A23, r2, w0, w1, w2)
    IMUL_TO(A30, A31, A32, A33, r3, w0, w1, w2)
    CMUL_ROW(0) CMUL_ROW(1) CMUL_ROW(2) CMUL_ROW(3)
  }

  // combine: O = P0 @ P1
  if (half == 1) {
#pragma unroll
    for (int i = 0; i < 16; i++) P[lane][i] = c[i];
  }
  __syncthreads();
  if (half == 0) {
    float A00 = P[lane][0],  A01 = P[lane][1];
    float A02 = P[lane][2],  A03 = P[lane][3];
    float A10 = P[lane][4],  A11 = P[lane][5];
    float A12 = P[lane][6],  A13 = P[lane][7];
    float A20 = P[lane][8],  A21 = P[lane][9];
    float A22 = P[lane][10], A23 = P[lane][11];
    float A30 = P[lane][12], A31 = P[lane][13];
    float A32 = P[lane][14], A33 = P[lane][15];

    CMUL_ROW(0)
    CMUL_ROW(1)
    CMUL_ROW(2)
    CMUL_ROW(3)

    float4* o = O4 + ((size_t)b * NOUT + lane) * 4;
    o[0] = make_float4(c[0],  c[1],  c[2],  c[3]);
    o[1] = make_float4(c[4],  c[5],  c[6],  c[7]);
    o[2] = make_float4(c[8],  c[9],  c[10], c[11]);
    o[3] = make_float4(c[12], c[13], c[14], c[15]);
  }
}

extern "C" void kernel_launch(void* const* d_in, const int* in_sizes, int n_in,
                              void* d_out, int out_size, void* d_ws, size_t ws_size,
                              hipStream_t stream) {
  const float* I  = (const float*)d_in[0];
  const float* aW = (const float*)d_in[1];
  const float* uW = (const float*)d_in[2];
  const float* tW = (const float*)d_in[3];

  float4* WT = (float4*)d_ws;  // 192 KiB scratch for transposed WM

  build_wm_kernel<<<M_TOT / 256, 256, 0, stream>>>(aW, uW, tW, WT);
  chain_kernel<<<BATCH, 128, 0, stream>>>((const float4*)I, WT, (float4*)d_out);
}

// Round 7
// 56.713 us; speedup vs baseline: 1.1831x; 1.1831x over previous
//
#include <hip/hip_runtime.h>

// Problem constants (from reference): B=4096, N_IN=64, N_OUT=64, M=4096.
#define BATCH 4096
#define NIN   64
#define NOUT  64
#define M_TOT (NIN * NOUT)

// ---------------------------------------------------------------------------
// Kernel 1: build WM from (aW, uW, tW). One thread per m = j*64 + k.
// Transposed layout for coalesced main-kernel loads:
//   WT[(j*3 + q)*64 + k] = row q of matrix (j,k)  (quad = (Rq0,Rq1,Rq2,tq))
// bottom row [0,0,0,1] implicit. 192 KiB in d_ws.
// ---------------------------------------------------------------------------
__global__ __launch_bounds__(256) void build_wm_kernel(
    const float* __restrict__ aW, const float* __restrict__ uW,
    const float* __restrict__ tW, float4* __restrict__ WT) {
  int m = blockIdx.x * 256 + threadIdx.x;
  if (m >= M_TOT) return;
  int j = m >> 6, k = m & 63;

  float a  = aW[m];
  float ux = 1.f / (1.f + expf(-uW[3 * m + 0]));
  float uy = 1.f / (1.f + expf(-uW[3 * m + 1]));
  float uz = 1.f / (1.f + expf(-uW[3 * m + 2]));
  float inv = 1.f / sqrtf(ux * ux + uy * uy + uz * uz);
  ux *= inv; uy *= inv; uz *= inv;

  float sa = sinf(a), ca = cosf(a);
  float xx = ux * ux, yy = uy * uy, zz = uz * uz;
  float xy = ux * uy, xz = ux * uz, yz = uy * uz;

  float R00 = ca * (1.f - xx) + xx;
  float R01 = -sa * uz + ca * (-xy) + xy;
  float R02 =  sa * uy + ca * (-xz) + xz;
  float R10 =  sa * uz + ca * (-xy) + xy;
  float R11 = ca * (1.f - yy) + yy;
  float R12 = -sa * ux + ca * (-yz) + yz;
  float R20 = -sa * uy + ca * (-xz) + xz;
  float R21 =  sa * ux + ca * (-yz) + yz;
  float R22 = ca * (1.f - zz) + zz;

  float t0 = tW[3 * m + 0], t1 = tW[3 * m + 1], t2 = tW[3 * m + 2];

  WT[(j * 3 + 0) * 64 + k] = make_float4(R00, R01, R02, t0);
  WT[(j * 3 + 1) * 64 + k] = make_float4(R10, R11, R12, t1);
  WT[(j * 3 + 2) * 64 + k] = make_float4(R20, R21, R22, t2);
}

// ---------------------------------------------------------------------------
// Kernel 2: chain product; 2-way j-split x 2 batch rows per thread (ILP).
// Block = 128 threads = 2 waves; block handles b0=2*blk, b1=b0+1:
//   wave 0: j in [0,32) for BOTH b's -> P0(b0), P0(b1)
//   wave 1: j in [32,64) for BOTH    -> P1(b0), P1(b1)
// lane = k. The two chains are independent FMA streams (2x ILP to cover
// load latency) and SHARE the per-j W loads (W overhead per chain halved).
// I loads via wave-uniform scalar pointers (s_load -> SGPR, scalar pipe —
// round 6 showed in-loop ds_read saturates the per-CU LDS pipe ~83%).
// W loads lane-coalesced, L1/L2-resident. Combine O = P0 @ P1 via LDS.
// NO register cap (round-2 lesson: forced VGPR=32 -> 200MB scratch spill).
// ---------------------------------------------------------------------------

// write A-row (4 dests) from I-row r and affine W rows W0..W2
#define IMUL_TO(D0, D1, D2, D3, r, W0, W1, W2)                       \
  D0 = r.x * W0.x + r.y * W1.x + r.z * W2.x;                         \
  D1 = r.x * W0.y + r.y * W1.y + r.z * W2.y;                         \
  D2 = r.x * W0.z + r.y * W1.z + r.z * W2.z;                         \
  D3 = r.x * W0.w + r.y * W1.w + r.z * W2.w + r.w;

// fold A (A00..A33) into carry array cc
#define CMUL_ROW_G(cc, x)                                                      \
  {                                                                            \
    float t0 = cc[x*4+0]*A00 + cc[x*4+1]*A10 + cc[x*4+2]*A20 + cc[x*4+3]*A30;  \
    float t1 = cc[x*4+0]*A01 + cc[x*4+1]*A11 + cc[x*4+2]*A21 + cc[x*4+3]*A31;  \
    float t2 = cc[x*4+0]*A02 + cc[x*4+1]*A12 + cc[x*4+2]*A22 + cc[x*4+3]*A32;  \
    float t3 = cc[x*4+0]*A03 + cc[x*4+1]*A13 + cc[x*4+2]*A23 + cc[x*4+3]*A33;  \
    cc[x*4+0] = t0; cc[x*4+1] = t1; cc[x*4+2] = t2; cc[x*4+3] = t3;            \
  }

// A = I_rows @ W(w0,w1,w2), then cc = cc @ A
#define STEP_FOLD_G(cc, Ibase, JJ)                                             \
  {                                                                            \
    float4 r0 = Ibase[(JJ) * 4 + 0], r1 = Ibase[(JJ) * 4 + 1];                 \
    float4 r2 = Ibase[(JJ) * 4 + 2], r3 = Ibase[(JJ) * 4 + 3];                 \
    float A00, A01, A02, A03, A10, A11, A12, A13;                              \
    float A20, A21, A22, A23, A30, A31, A32, A33;                              \
    IMUL_TO(A00, A01, A02, A03, r0, w0, w1, w2)                                \
    IMUL_TO(A10, A11, A12, A13, r1, w0, w1, w2)                                \
    IMUL_TO(A20, A21, A22, A23, r2, w0, w1, w2)                                \
    IMUL_TO(A30, A31, A32, A33, r3, w0, w1, w2)                                \
    CMUL_ROW_G(cc, 0) CMUL_ROW_G(cc, 1) CMUL_ROW_G(cc, 2) CMUL_ROW_G(cc, 3)   \
  }

__global__ __launch_bounds__(128) void chain_kernel(
    const float4* __restrict__ I4, const float4* __restrict__ WT,
    float4* __restrict__ O4) {
  const int lane = threadIdx.x & 63;
  const int half = threadIdx.x >> 6;  // 0: j in [0,32), 1: j in [32,64)
  const int b0   = (int)blockIdx.x * 2;

  // wave-uniform scalar I bases -> s_load, rows live in SGPRs
  const int ioff0 = __builtin_amdgcn_readfirstlane((b0 * NIN + half * 32) * 4);
  const float4* __restrict__ Ib0 = I4 + ioff0;
  const float4* __restrict__ Ib1 = Ib0 + NIN * 4;  // b1 = b0 + 1
  const float4* __restrict__ Wb  = WT + (size_t)(half * 32 * 3) * 64 + lane;

  float c0[16], c1[16];

  {  // peeled j=0: c = A directly (skip identity multiply)
    float4 w0 = Wb[0], w1 = Wb[64], w2 = Wb[128];
    float4 r0 = Ib0[0], r1 = Ib0[1], r2 = Ib0[2], r3 = Ib0[3];
    IMUL_TO(c0[0],  c0[1],  c0[2],  c0[3],  r0, w0, w1, w2)
    IMUL_TO(c0[4],  c0[5],  c0[6],  c0[7],  r1, w0, w1, w2)
    IMUL_TO(c0[8],  c0[9],  c0[10], c0[11], r2, w0, w1, w2)
    IMUL_TO(c0[12], c0[13], c0[14], c0[15], r3, w0, w1, w2)
    float4 s0 = Ib1[0], s1 = Ib1[1], s2 = Ib1[2], s3 = Ib1[3];
    IMUL_TO(c1[0],  c1[1],  c1[2],  c1[3],  s0, w0, w1, w2)
    IMUL_TO(c1[4],  c1[5],  c1[6],  c1[7],  s1, w0, w1, w2)
    IMUL_TO(c1[8],  c1[9],  c1[10], c1[11], s2, w0, w1, w2)
    IMUL_TO(c1[12], c1[13], c1[14], c1[15], s3, w0, w1, w2)
  }

#pragma unroll 4
  for (int j = 1; j < 32; ++j) {
    float4 w0 = Wb[j * 192], w1 = Wb[j * 192 + 64], w2 = Wb[j * 192 + 128];
    STEP_FOLD_G(c0, Ib0, j)
    STEP_FOLD_G(c1, Ib1, j)
  }

  // combine: O = P0 @ P1 for both b's
  __shared__ float P[2][64][17];  // padded stride 17 -> conflict-free
  if (half == 1) {
#pragma unroll
    for (int i = 0; i < 16; i++) P[0][lane][i] = c0[i];
#pragma unroll
    for (int i = 0; i < 16; i++) P[1][lane][i] = c1[i];
  }
  __syncthreads();
  if (half == 0) {
    {
      float A00 = P[0][lane][0],  A01 = P[0][lane][1];
      float A02 = P[0][lane][2],  A03 = P[0][lane][3];
      float A10 = P[0][lane][4],  A11 = P[0][lane][5];
      float A12 = P[0][lane][6],  A13 = P[0][lane][7];
      float A20 = P[0][lane][8],  A21 = P[0][lane][9];
      float A22 = P[0][lane][10], A23 = P[0][lane][11];
      float A30 = P[0][lane][12], A31 = P[0][lane][13];
      float A32 = P[0][lane][14], A33 = P[0][lane][15];
      CMUL_ROW_G(c0, 0) CMUL_ROW_G(c0, 1) CMUL_ROW_G(c0, 2) CMUL_ROW_G(c0, 3)
      float4* o = O4 + ((size_t)b0 * NOUT + lane) * 4;
      o[0] = make_float4(c0[0],  c0[1],  c0[2],  c0[3]);
      o[1] = make_float4(c0[4],  c0[5],  c0[6],  c0[7]);
      o[2] = make_float4(c0[8],  c0[9],  c0[10], c0[11]);
      o[3] = make_float4(c0[12], c0[13], c0[14], c0[15]);
    }
    {
      float A00 = P[1][lane][0],  A01 = P[1][lane][1];
      float A02 = P[1][lane][2],  A03 = P[1][lane][3];
      float A10 = P[1][lane][4],  A11 = P[1][lane][5];
      float A12 = P[1][lane][6],  A13 = P[1][lane][7];
      float A20 = P[1][lane][8],  A21 = P[1][lane][9];
      float A22 = P[1][lane][10], A23 = P[1][lane][11];
      float A30 = P[1][lane][12], A31 = P[1][lane][13];
      float A32 = P[1][lane][14], A33 = P[1][lane][15];
      CMUL_ROW_G(c1, 0) CMUL_ROW_G(c1, 1) CMUL_ROW_G(c1, 2) CMUL_ROW_G(c1, 3)
      float4* o = O4 + ((size_t)(b0 + 1) * NOUT + lane) * 4;
      o[0] = make_float4(c1[0],  c1[1],  c1[2],  c1[3]);
      o[1] = make_float4(c1[4],  c1[5],  c1[6],  c1[7]);
      o[2] = make_float4(c1[8],  c1[9],  c1[10], c1[11]);
      o[3] = make_float4(c1[12], c1[13], c1[14], c1[15]);
    }
  }
}

extern "C" void kernel_launch(void* const* d_in, const int* in_sizes, int n_in,
                              void* d_out, int out_size, void* d_ws, size_t ws_size,
                              hipStream_t stream) {
  const float* I  = (const float*)d_in[0];
  const float* aW = (const float*)d_in[1];
  const float* uW = (const float*)d_in[2];
  const float* tW = (const float*)d_in[3];

  float4* WT = (float4*)d_ws;  // 192 KiB scratch for transposed WM

  build_wm_kernel<<<M_TOT / 256, 256, 0, stream>>>(aW, uW, tW, WT);
  chain_kernel<<<BATCH / 2, 128, 0, stream>>>((const float4*)I, WT, (float4*)d_out);
}